// Round 3
// baseline (10040.549 us; speedup 1.0000x reference)
//
#include <hip/hip_runtime.h>
#include <math.h>

#define N_NODES 100000
#define N_EDGES 3200000
#define DIM 256
#define SCAN_B 1024
#define NPASS 8
#define WIN ((N_NODES + NPASS - 1) / NPASS)  // 12500

// src-window bucketing: window = src >> WSH (2048 nodes = 1.0 MB of xw rows)
#define WSH 11
#define NW 49                         // ceil(100000/2048)
#define NBUCK (NW * N_NODES)          // 4,900,000 buckets, window-major [w][dst]
#define SCAN_GRID_W ((NBUCK + SCAN_B - 1) / SCAN_B)  // 4786
#define BS_CHUNK ((SCAN_GRID_W + 1023) / 1024)       // 5

// aggregate geometry: block owns NPB contiguous dst nodes, LDS f32 accum
#define NPB 64                        // 64 KB LDS -> 2 blocks/CU
#define AGG_GRID ((N_NODES + NPB - 1) / NPB)  // 1563
#define PACK_SH 17                    // colidx word = (dst&63)<<17 | src
#define SRC_MASK 0x1FFFF

typedef unsigned short u16;
typedef unsigned int u32;
typedef __attribute__((ext_vector_type(8))) short bf16x8;
typedef __attribute__((ext_vector_type(4))) float f32x4;

__device__ __forceinline__ float bf2f(u16 u) {
    union { u32 i; float f; } v; v.i = ((u32)u) << 16; return v.f;
}
__device__ __forceinline__ u16 f2bf(float f) {
    union { float f; u32 i; } v; v.f = f;
    u32 x = v.i;
    return (u16)((x + 0x7fffu + ((x >> 16) & 1u)) >> 16);
}
__device__ __forceinline__ float sane(float v) {
    union { float f; u32 i; } u; u.f = v;
    if ((u.i & 0x7f800000u) == 0x7f800000u) return 0.f;
    return v;
}
__device__ __forceinline__ int iclamp(int v, int lo, int hi) {
    return v < lo ? lo : (v > hi ? hi : v);
}

// ---- runtime format probes ----------------------------------------------
// flags[0]: 1 => float tensors are fp32, 0 => bf16
// flags[1]: 1 => edge_index is int64 (lo/hi word pairs), 0 => int32
__global__ void detect_kernel(const u32* __restrict__ xw_words,
                              const int* __restrict__ ei, int* __restrict__ flags) {
    int lane = threadIdx.x;
    int cnt = 0;
#pragma unroll
    for (int j = 0; j < 4; ++j) {
        u32 e = (xw_words[lane + 64 * j] >> 7) & 0xffu;
        cnt += (e >= 0x70 && e <= 0x88) ? 1 : 0;
    }
    int nz = 0;
#pragma unroll
    for (int j = 0; j < 4; ++j) nz += (ei[2 * (lane + 64 * j) + 1] != 0) ? 1 : 0;
#pragma unroll
    for (int off = 32; off; off >>= 1) {
        cnt += __shfl_down(cnt, off, 64);
        nz += __shfl_down(nz, off, 64);
    }
    if (lane == 0) {
        flags[0] = (cnt < 128) ? 1 : 0;
        flags[1] = (nz == 0) ? 1 : 0;
    }
}

__device__ __forceinline__ int edge_val(const int* __restrict__ ei, int which,
                                        int i, int f64) {
    long long idx = (long long)which * N_EDGES + i;
    int v = f64 ? ei[idx * 2] : ei[idx];
    return iclamp(v, 0, N_NODES - 1);
}

// ---- canonicalize x to internal bf16 ------------------------------------
__global__ void convert_x(const void* __restrict__ xin, u16* __restrict__ xbf,
                          const int* __restrict__ flags) {
    long long i = (long long)blockIdx.x * blockDim.x + threadIdx.x;
    if (i >= (long long)N_NODES * DIM) return;
    float v = flags[0] ? ((const float*)xin)[i] : bf2f(((const u16*)xin)[i]);
    xbf[i] = f2bf(sane(v));
}

// ---- bucket-CSR build: count per (src-window, dst) ----------------------
__global__ void count_convert(const int* __restrict__ ei, int* __restrict__ cntW,
                              int* __restrict__ src32, int* __restrict__ dst32,
                              const int* __restrict__ flags) {
    int i = blockIdx.x * blockDim.x + threadIdx.x;
    if (i < N_EDGES) {
        int f = flags[1];
        int s = edge_val(ei, 0, i, f);
        int d = edge_val(ei, 1, i, f);
        src32[i] = s;
        dst32[i] = d;
        int w = s >> WSH;
        atomicAdd(&cntW[w * N_NODES + d], 1);
    }
}

// dis from in-degree = sum of the node's bucket counts over windows
__global__ void deg_dis(const int* __restrict__ cntW, float* __restrict__ dis) {
    int i = blockIdx.x * blockDim.x + threadIdx.x;
    if (i < N_NODES) {
        int d = 0;
        for (int w = 0; w < NW; ++w) d += cntW[w * N_NODES + i];
        d = iclamp(d, 0, N_EDGES);
        dis[i] = rsqrtf((float)(d + 1));  // +1 self loop
    }
}

// ---- parallel 3-phase exclusive scan over NBUCK elements ----------------
__global__ __launch_bounds__(SCAN_B) void scan_block_sums(const int* __restrict__ cnt,
                                                          int* __restrict__ bsum,
                                                          int M) {
    __shared__ int ws[16];
    int i = blockIdx.x * SCAN_B + threadIdx.x;
    int v = (i < M) ? cnt[i] : 0;
#pragma unroll
    for (int off = 32; off; off >>= 1) v += __shfl_down(v, off, 64);
    if ((threadIdx.x & 63) == 0) ws[threadIdx.x >> 6] = v;
    __syncthreads();
    if (threadIdx.x < 16) {
        int t = ws[threadIdx.x];
#pragma unroll
        for (int off = 8; off; off >>= 1) t += __shfl_down(t, off, 16);
        if (threadIdx.x == 0) bsum[blockIdx.x] = t;
    }
}

// single-block scan of SCAN_GRID_W block sums; 1024 thr x BS_CHUNK elems
__global__ __launch_bounds__(1024) void scan_bsum_big(int* __restrict__ bsum) {
    __shared__ int sd[1024];
    int t = threadIdx.x;
    int base = t * BS_CHUNK;
    int v[BS_CHUNK];
    int s = 0;
#pragma unroll
    for (int j = 0; j < BS_CHUNK; ++j) {
        v[j] = (base + j < SCAN_GRID_W) ? bsum[base + j] : 0;
        s += v[j];
    }
    sd[t] = s;
    __syncthreads();
    for (int off = 1; off < 1024; off <<= 1) {
        int x = (t >= off) ? sd[t - off] : 0;
        __syncthreads();
        sd[t] += x;
        __syncthreads();
    }
    int ex = sd[t] - s;
#pragma unroll
    for (int j = 0; j < BS_CHUNK; ++j) {
        if (base + j < SCAN_GRID_W) { bsum[base + j] = ex; ex += v[j]; }
    }
}

__global__ __launch_bounds__(SCAN_B) void scan_final_w(const int* __restrict__ cnt,
                                                       const int* __restrict__ bsum,
                                                       int* __restrict__ rowptr,
                                                       int* __restrict__ cursor,
                                                       int M) {
    __shared__ int ws[16];
    int lane = threadIdx.x & 63;
    int wid = threadIdx.x >> 6;
    int i = blockIdx.x * SCAN_B + threadIdx.x;
    int c = (i < M) ? cnt[i] : 0;
    int v = c;
#pragma unroll
    for (int off = 1; off < 64; off <<= 1) {
        int t = __shfl_up(v, off, 64);
        if (lane >= off) v += t;
    }
    if (lane == 63) ws[wid] = v;
    __syncthreads();
    int woff = 0;
    for (int w = 0; w < wid; ++w) woff += ws[w];
    int excl = bsum[blockIdx.x] + woff + v - c;
    if (i < M) { rowptr[i] = excl; cursor[i] = excl; }
    if (blockIdx.x == 0 && threadIdx.x == 0) rowptr[M] = N_EDGES;
}

// ---- windowed CSR fill: pass p handles dst in [lo, lo+WIN) --------------
// colidx word packs (dst % NPB) in bits 17..22, src in bits 0..16.
__global__ void fill_csr_pass(const int* __restrict__ src32,
                              const int* __restrict__ dst32,
                              int* __restrict__ cursorW, u32* __restrict__ colidx,
                              int lo) {
    int i = blockIdx.x * blockDim.x + threadIdx.x;
    if (i < N_EDGES) {
        int d = dst32[i];
        if ((unsigned)(d - lo) < (unsigned)WIN) {
            int s = src32[i];
            int w = s >> WSH;
            int pos = atomicAdd(&cursorW[w * N_NODES + d], 1);
            colidx[pos] = ((u32)(d & (NPB - 1)) << PACK_SH) | (u32)s;
        }
    }
}

// ---- weight transpose (dtype-aware) -------------------------------------
__global__ void transpose_w(const void* __restrict__ W, u16* __restrict__ Wt,
                            const int* __restrict__ flags) {
    int n = blockIdx.x;
    int k = threadIdx.x;
    float v = flags[0] ? ((const float*)W)[k * DIM + n]
                       : bf2f(((const u16*)W)[k * DIM + n]);
    Wt[n * DIM + k] = f2bf(sane(v));
}

// ---- dense GEMM: register-resident B, dis-prescaled output --------------
// out[row] = bf16( dis[row] * (A[row] @ W) )
__global__ __launch_bounds__(256) void gemm_mfma(const u16* __restrict__ A,
                                                 const u16* __restrict__ Wt,
                                                 const float* __restrict__ dis,
                                                 u16* __restrict__ out) {
    int w = threadIdx.x >> 6;   // col-group 0..3
    int lane = threadIdx.x & 63;
    int rt = blockIdx.x;        // row tile (100000/16 = 6250 exact)
    int m = lane & 15;
    int quad = lane >> 4;

    bf16x8 B[4][8];
#pragma unroll
    for (int t2 = 0; t2 < 4; ++t2)
#pragma unroll
        for (int ks = 0; ks < 8; ++ks)
            B[t2][ks] = *(const bf16x8*)(Wt + (size_t)((w * 4 + t2) * 16 + m) * DIM +
                                         ks * 32 + quad * 8);

    const u16* arow = A + (size_t)(rt * 16 + m) * DIM + quad * 8;
    f32x4 acc[4];
#pragma unroll
    for (int t2 = 0; t2 < 4; ++t2) acc[t2] = (f32x4){0.f, 0.f, 0.f, 0.f};

#pragma unroll
    for (int ks = 0; ks < 8; ++ks) {
        bf16x8 a = *(const bf16x8*)(arow + ks * 32);
#pragma unroll
        for (int t2 = 0; t2 < 4; ++t2)
            acc[t2] = __builtin_amdgcn_mfma_f32_16x16x32_bf16(a, B[t2][ks], acc[t2], 0, 0, 0);
    }

    float4 dv = *(const float4*)(dis + rt * 16 + quad * 4);
    float dr[4] = {dv.x, dv.y, dv.z, dv.w};

#pragma unroll
    for (int t2 = 0; t2 < 4; ++t2) {
#pragma unroll
        for (int r = 0; r < 4; ++r) {
            int row = rt * 16 + quad * 4 + r;
            int c = w * 64 + t2 * 16 + m;
            out[(size_t)row * DIM + c] = f2bf(sane(acc[t2][r] * dr[r]));
        }
    }
}

// ---- windowed aggregation, LDS accumulators, edge-parallel --------------
// Block owns NPB=64 contiguous dst nodes with f32 accum [64][256] in LDS.
// Sweep windows 0..NW-1; block's edges in window w are the contiguous slice
// [bptr[w*N+n0], bptr[w*N+nlast]) -> waves take contiguous chunks, unroll 8.
// Gather = 4 strided ushort loads (col = lane + q*64, 128B coalesced each);
// accumulate with ds_add_f32 at dword dl*256 + lane + q*64 (bank = lane%32,
// 2-way = conflict-free). xw rows are dis-prescaled by the GEMM epilogue.
__global__ __launch_bounds__(256, 2) void aggregate(const u16* __restrict__ xw,
                                                    const int* __restrict__ bptr,
                                                    const u32* __restrict__ colidx,
                                                    const float* __restrict__ dis,
                                                    const void* __restrict__ bias,
                                                    void* __restrict__ out,
                                                    const int* __restrict__ flags,
                                                    int final_layer) {
    __shared__ float acc[NPB * DIM];  // 64 KB
    int t = threadIdx.x;
    int wv = t >> 6;
    int lane = t & 63;
    int n0 = blockIdx.x * NPB;
    int nlast = n0 + NPB;
    if (nlast > N_NODES) nlast = N_NODES;

    for (int i = t; i < NPB * DIM; i += 256) acc[i] = 0.f;
    __syncthreads();

#define LOADE(k, vk)                                                   \
    u32 s##k = (vk) & SRC_MASK;                                        \
    u32 d##k = (vk) >> PACK_SH;                                        \
    const u16* r##k = xw + ((size_t)s##k << 8);                        \
    u16 A##k = r##k[lane];                                             \
    u16 B##k = r##k[lane + 64];                                        \
    u16 C##k = r##k[lane + 128];                                       \
    u16 D##k = r##k[lane + 192];

#define ADDE(k)                                                        \
    {                                                                  \
        float* ap = acc + d##k * DIM + lane;                           \
        atomicAdd(ap, bf2f(A##k));                                     \
        atomicAdd(ap + 64, bf2f(B##k));                                \
        atomicAdd(ap + 128, bf2f(C##k));                               \
        atomicAdd(ap + 192, bf2f(D##k));                               \
    }

    for (int w = 0; w < NW; ++w) {
        int B0 = bptr[w * N_NODES + n0];
        int B1 = bptr[w * N_NODES + nlast];
        int cnt = B1 - B0;
        int per = (cnt + 3) >> 2;
        int e = B0 + wv * per;
        int s1 = e + per;
        if (s1 > B1) s1 = B1;
        for (; e + 8 <= s1; e += 8) {
            u32 v0 = colidx[e], v1 = colidx[e + 1], v2 = colidx[e + 2],
                v3 = colidx[e + 3], v4 = colidx[e + 4], v5 = colidx[e + 5],
                v6 = colidx[e + 6], v7 = colidx[e + 7];
            LOADE(0, v0) LOADE(1, v1) LOADE(2, v2) LOADE(3, v3)
            LOADE(4, v4) LOADE(5, v5) LOADE(6, v6) LOADE(7, v7)
            ADDE(0) ADDE(1) ADDE(2) ADDE(3)
            ADDE(4) ADDE(5) ADDE(6) ADDE(7)
        }
        for (; e < s1; ++e) {
            u32 v = colidx[e];
            LOADE(9, v)
            ADDE(9)
        }
    }
#undef LOADE
#undef ADDE
    __syncthreads();

    // epilogue: o = dis[n]*(acc + self) + bias, ELU, store (strided cols)
    int f32mode = flags[0];
    float b0, b1, b2, b3;
    if (f32mode) {
        const float* bp = (const float*)bias;
        b0 = bp[lane]; b1 = bp[lane + 64]; b2 = bp[lane + 128]; b3 = bp[lane + 192];
    } else {
        const u16* bp = (const u16*)bias;
        b0 = bf2f(bp[lane]); b1 = bf2f(bp[lane + 64]);
        b2 = bf2f(bp[lane + 128]); b3 = bf2f(bp[lane + 192]);
    }
    for (int ln = wv * (NPB / 4); ln < (wv + 1) * (NPB / 4); ++ln) {
        int n = n0 + ln;
        if (n >= N_NODES) break;
        float dn = dis[n];
        const u16* xr = xw + ((size_t)n << 8);
        const float* ap = acc + ln * DIM + lane;
        float o0 = dn * (ap[0]   + bf2f(xr[lane]))       + b0;
        float o1 = dn * (ap[64]  + bf2f(xr[lane + 64]))  + b1;
        float o2 = dn * (ap[128] + bf2f(xr[lane + 128])) + b2;
        float o3 = dn * (ap[192] + bf2f(xr[lane + 192])) + b3;
        o0 = sane(o0 > 0.f ? o0 : expm1f(o0));
        o1 = sane(o1 > 0.f ? o1 : expm1f(o1));
        o2 = sane(o2 > 0.f ? o2 : expm1f(o2));
        o3 = sane(o3 > 0.f ? o3 : expm1f(o3));
        if (final_layer && f32mode) {
            float* op = (float*)out + (size_t)n * DIM + lane;
            op[0] = o0; op[64] = o1; op[128] = o2; op[192] = o3;
        } else {
            u16* op = (u16*)out + (size_t)n * DIM + lane;
            op[0] = f2bf(o0); op[64] = f2bf(o1);
            op[128] = f2bf(o2); op[192] = f2bf(o3);
        }
    }
}

// ---- launch -------------------------------------------------------------
extern "C" void kernel_launch(void* const* d_in, const int* in_sizes, int n_in,
                              void* d_out, int out_size, void* d_ws, size_t ws_size,
                              hipStream_t stream) {
    const void* x  = d_in[0];
    const int*  ei = (const int*)d_in[1];
    const void* W1 = d_in[2];
    const void* b1 = d_in[3];
    const void* W2 = d_in[4];
    const void* b2 = d_in[5];

    char* ws = (char*)d_ws;
    size_t off = 0;
    auto alloc = [&](size_t bytes) {
        void* p = ws + off;
        off = (off + bytes + 255) & ~(size_t)255;
        return p;
    };
    int*   flags   = (int*)alloc(256);
    int*   rowptrW = (int*)alloc(((size_t)NBUCK + 1) * 4);  // 19.6 MB, persists
    u32*   colidx  = (u32*)alloc((size_t)N_EDGES * 4);      // 12.8 MB
    float* dis     = (float*)alloc((size_t)N_NODES * 4);
    int*   bsum    = (int*)alloc((size_t)SCAN_GRID_W * 4 + 256);
    u16*   Wt      = (u16*)alloc((size_t)DIM * DIM * 2);
    u16*   xw      = (u16*)alloc((size_t)N_NODES * DIM * 2);  // 51.2 MB
    (void)ws_size;

    // CSR-build temporaries alias the xw region (dead before gemm writes xw):
    // src32 12.8MB | dst32 12.8MB | cntW 19.6MB  (cursorW aliases cntW: the
    // counts are consumed by deg_dis/scan before scan_final_w overwrites
    // each element in-place with the cursor value)
    char* xwb = (char*)xw;
    int* src32   = (int*)xwb;
    int* dst32   = (int*)(xwb + (size_t)N_EDGES * 4);
    int* cntW    = (int*)(xwb + (size_t)N_EDGES * 8);
    int* cursorW = cntW;

    u16* xbf = (u16*)d_out;  // d_out doubles as bf16-x scratch, then h

    detect_kernel<<<1, 64, 0, stream>>>((const u32*)x, ei, flags);
    hipMemsetAsync(cntW, 0, (size_t)NBUCK * 4, stream);
    count_convert<<<(N_EDGES + 255) / 256, 256, 0, stream>>>(ei, cntW, src32, dst32, flags);
    deg_dis<<<(N_NODES + 255) / 256, 256, 0, stream>>>(cntW, dis);
    scan_block_sums<<<SCAN_GRID_W, SCAN_B, 0, stream>>>(cntW, bsum, NBUCK);
    scan_bsum_big<<<1, 1024, 0, stream>>>(bsum);
    scan_final_w<<<SCAN_GRID_W, SCAN_B, 0, stream>>>(cntW, bsum, rowptrW, cursorW, NBUCK);
    for (int p = 0; p < NPASS; ++p)
        fill_csr_pass<<<(N_EDGES + 255) / 256, 256, 0, stream>>>(src32, dst32, cursorW,
                                                                 colidx, p * WIN);
    convert_x<<<(N_NODES * DIM + 255) / 256, 256, 0, stream>>>(x, xbf, flags);

    // layer 1
    transpose_w<<<DIM, DIM, 0, stream>>>(W1, Wt, flags);
    gemm_mfma<<<N_NODES / 16, 256, 0, stream>>>(xbf, Wt, dis, xw);
    aggregate<<<AGG_GRID, 256, 0, stream>>>(xw, rowptrW, colidx, dis, b1, d_out, flags, 0);

    // layer 2
    transpose_w<<<DIM, DIM, 0, stream>>>(W2, Wt, flags);
    gemm_mfma<<<N_NODES / 16, 256, 0, stream>>>((const u16*)d_out, Wt, dis, xw);
    aggregate<<<AGG_GRID, 256, 0, stream>>>(xw, rowptrW, colidx, dis, b2, d_out, flags, 1);
}

// Round 4
// 1201.642 us; speedup vs baseline: 8.3557x; 8.3557x over previous
//
#include <hip/hip_runtime.h>
#include <math.h>

#define N_NODES 100000
#define N_EDGES 3200000
#define DIM 256
#define SCAN_B 1024
#define SCAN_NBLK ((N_NODES + SCAN_B - 1) / SCAN_B)  // 98
#define NPASS 8
#define WIN ((N_NODES + NPASS - 1) / NPASS)  // 12500

typedef unsigned short u16;
typedef unsigned int u32;
typedef __attribute__((ext_vector_type(8))) short bf16x8;
typedef __attribute__((ext_vector_type(4))) float f32x4;

__device__ __forceinline__ float bf2f(u16 u) {
    union { u32 i; float f; } v; v.i = ((u32)u) << 16; return v.f;
}
__device__ __forceinline__ u16 f2bf(float f) {
    union { float f; u32 i; } v; v.f = f;
    u32 x = v.i;
    return (u16)((x + 0x7fffu + ((x >> 16) & 1u)) >> 16);
}
__device__ __forceinline__ float sane(float v) {
    union { float f; u32 i; } u; u.f = v;
    if ((u.i & 0x7f800000u) == 0x7f800000u) return 0.f;
    return v;
}
__device__ __forceinline__ int iclamp(int v, int lo, int hi) {
    return v < lo ? lo : (v > hi ? hi : v);
}
// one dword holding 2 bf16 -> float2 (lo elem, hi elem)
__device__ __forceinline__ float2 cvt2(u32 d) {
    union { u32 i; float f; } lo, hi;
    lo.i = d << 16;
    hi.i = d & 0xffff0000u;
    return make_float2(lo.f, hi.f);
}

// ---- runtime format probes ----------------------------------------------
// flags[0]: 1 => float tensors are fp32, 0 => bf16
// flags[1]: 1 => edge_index is int64 (lo/hi word pairs), 0 => int32
__global__ void detect_kernel(const u32* __restrict__ xw_words,
                              const int* __restrict__ ei, int* __restrict__ flags) {
    int lane = threadIdx.x;
    int cnt = 0;
#pragma unroll
    for (int j = 0; j < 4; ++j) {
        u32 e = (xw_words[lane + 64 * j] >> 7) & 0xffu;
        cnt += (e >= 0x70 && e <= 0x88) ? 1 : 0;
    }
    int nz = 0;
#pragma unroll
    for (int j = 0; j < 4; ++j) nz += (ei[2 * (lane + 64 * j) + 1] != 0) ? 1 : 0;
#pragma unroll
    for (int off = 32; off; off >>= 1) {
        cnt += __shfl_down(cnt, off, 64);
        nz += __shfl_down(nz, off, 64);
    }
    if (lane == 0) {
        flags[0] = (cnt < 128) ? 1 : 0;
        flags[1] = (nz == 0) ? 1 : 0;
    }
}

__device__ __forceinline__ int edge_val(const int* __restrict__ ei, int which,
                                        int i, int f64) {
    long long idx = (long long)which * N_EDGES + i;
    int v = f64 ? ei[idx * 2] : ei[idx];
    return iclamp(v, 0, N_NODES - 1);
}

// ---- CSR build: count + int32 conversion fused --------------------------
__global__ void count_convert(const int* __restrict__ ei, int* __restrict__ rowcount,
                              int* __restrict__ src32, int* __restrict__ dst32,
                              const int* __restrict__ flags) {
    int i = blockIdx.x * blockDim.x + threadIdx.x;
    if (i < N_EDGES) {
        int f = flags[1];
        int s = edge_val(ei, 0, i, f);
        int d = edge_val(ei, 1, i, f);
        src32[i] = s;
        dst32[i] = d;
        atomicAdd(&rowcount[d], 1);
    }
}

// ---- parallel 3-phase exclusive scan ------------------------------------
__global__ __launch_bounds__(SCAN_B) void scan_block_sums(const int* __restrict__ cnt,
                                                          int* __restrict__ bsum) {
    __shared__ int ws[16];
    int i = blockIdx.x * SCAN_B + threadIdx.x;
    int v = (i < N_NODES) ? cnt[i] : 0;
#pragma unroll
    for (int off = 32; off; off >>= 1) v += __shfl_down(v, off, 64);
    if ((threadIdx.x & 63) == 0) ws[threadIdx.x >> 6] = v;
    __syncthreads();
    if (threadIdx.x < 16) {
        int t = ws[threadIdx.x];
#pragma unroll
        for (int off = 8; off; off >>= 1) t += __shfl_down(t, off, 16);
        if (threadIdx.x == 0) bsum[blockIdx.x] = t;
    }
}

__global__ void scan_bsum(int* __restrict__ bsum, int* __restrict__ rowptr) {
    __shared__ int sdata[128];
    int i = threadIdx.x;  // 128 threads
    int v = (i < SCAN_NBLK) ? bsum[i] : 0;
    sdata[i] = v;
    __syncthreads();
    for (int off = 1; off < 128; off <<= 1) {
        int t = (i >= off) ? sdata[i - off] : 0;
        __syncthreads();
        sdata[i] += t;
        __syncthreads();
    }
    if (i < SCAN_NBLK) bsum[i] = sdata[i] - v;  // exclusive
    if (i == 0) rowptr[N_NODES] = sdata[127];   // total = E
}

// scan_final with dis computation fused (dis = rsqrt(indeg+1))
__global__ __launch_bounds__(SCAN_B) void scan_final(const int* __restrict__ cnt,
                                                     const int* __restrict__ bsum,
                                                     int* __restrict__ rowptr,
                                                     int* __restrict__ cursor,
                                                     float* __restrict__ dis) {
    __shared__ int ws[16];
    int lane = threadIdx.x & 63;
    int wid = threadIdx.x >> 6;
    int i = blockIdx.x * SCAN_B + threadIdx.x;
    int c = (i < N_NODES) ? cnt[i] : 0;
    int v = c;
#pragma unroll
    for (int off = 1; off < 64; off <<= 1) {
        int t = __shfl_up(v, off, 64);
        if (lane >= off) v += t;
    }
    if (lane == 63) ws[wid] = v;
    __syncthreads();
    int woff = 0;
    for (int w = 0; w < wid; ++w) woff += ws[w];
    int excl = bsum[blockIdx.x] + woff + v - c;
    if (i < N_NODES) {
        rowptr[i] = excl;
        cursor[i] = excl;
        dis[i] = rsqrtf((float)(iclamp(c, 0, N_EDGES) + 1));  // +1 self loop
    }
}

// ---- windowed CSR fill: pass p handles dst in [lo, lo+WIN) --------------
// scatter window ~1.6 MB -> L2-resident, kills the 16x write amplification
__global__ void fill_csr_pass(const int* __restrict__ src32,
                              const int* __restrict__ dst32,
                              int* __restrict__ cursor, int* __restrict__ colidx,
                              int lo) {
    int i = blockIdx.x * blockDim.x + threadIdx.x;
    if (i < N_EDGES) {
        int d = dst32[i];
        if ((unsigned)(d - lo) < (unsigned)WIN) {
            int pos = atomicAdd(&cursor[d], 1);
            colidx[pos] = src32[i];
        }
    }
}

// ---- both weight transposes in one launch (dtype-aware) -----------------
__global__ void transpose_w2(const void* __restrict__ W1, const void* __restrict__ W2,
                             u16* __restrict__ Wt1, u16* __restrict__ Wt2,
                             const int* __restrict__ flags) {
    int n = blockIdx.x;
    int k = threadIdx.x;
    int f32mode = flags[0];
    float v1 = f32mode ? ((const float*)W1)[k * DIM + n]
                       : bf2f(((const u16*)W1)[k * DIM + n]);
    float v2 = f32mode ? ((const float*)W2)[k * DIM + n]
                       : bf2f(((const u16*)W2)[k * DIM + n]);
    Wt1[n * DIM + k] = f2bf(sane(v1));
    Wt2[n * DIM + k] = f2bf(sane(v2));
}

// ---- dense GEMM: register-resident B, dis-prescaled output --------------
// out[row] = bf16( dis[row] * (A[row] @ W) ).  A-load path converts/scrubs
// in place (first=1: A may be fp32 per flags[0]), eliminating convert_x.
__global__ __launch_bounds__(256) void gemm_mfma(const void* __restrict__ Ain,
                                                 const u16* __restrict__ Wt,
                                                 const float* __restrict__ dis,
                                                 u16* __restrict__ out,
                                                 const int* __restrict__ flags,
                                                 int first) {
    int w = threadIdx.x >> 6;   // col-group 0..3
    int lane = threadIdx.x & 63;
    int rt = blockIdx.x;        // row tile (100000/16 = 6250 exact)
    int m = lane & 15;
    int quad = lane >> 4;

    bf16x8 B[4][8];
#pragma unroll
    for (int t2 = 0; t2 < 4; ++t2)
#pragma unroll
        for (int ks = 0; ks < 8; ++ks)
            B[t2][ks] = *(const bf16x8*)(Wt + (size_t)((w * 4 + t2) * 16 + m) * DIM +
                                         ks * 32 + quad * 8);

    int f32in = first ? flags[0] : 0;
    size_t rowoff = (size_t)(rt * 16 + m) * DIM + quad * 8;  // element offset
    f32x4 acc[4];
#pragma unroll
    for (int t2 = 0; t2 < 4; ++t2) acc[t2] = (f32x4){0.f, 0.f, 0.f, 0.f};

#pragma unroll
    for (int ks = 0; ks < 8; ++ks) {
        bf16x8 a;
        if (f32in) {
            const float* ap = (const float*)Ain + rowoff + ks * 32;
            float4 f0 = *(const float4*)ap;
            float4 f1 = *(const float4*)(ap + 4);
            a[0] = (short)f2bf(sane(f0.x)); a[1] = (short)f2bf(sane(f0.y));
            a[2] = (short)f2bf(sane(f0.z)); a[3] = (short)f2bf(sane(f0.w));
            a[4] = (short)f2bf(sane(f1.x)); a[5] = (short)f2bf(sane(f1.y));
            a[6] = (short)f2bf(sane(f1.z)); a[7] = (short)f2bf(sane(f1.w));
        } else {
            union { bf16x8 v; u32 d[4]; } U;
            U.v = *(const bf16x8*)((const u16*)Ain + rowoff + ks * 32);
#pragma unroll
            for (int j = 0; j < 4; ++j) {   // scrub inf/nan bf16 -> 0
                u32 x = U.d[j];
                if ((x & 0x7f800000u) == 0x7f800000u) x &= 0x0000ffffu;
                if ((x & 0x00007f80u) == 0x00007f80u) x &= 0xffff0000u;
                U.d[j] = x;
            }
            a = U.v;
        }
#pragma unroll
        for (int t2 = 0; t2 < 4; ++t2)
            acc[t2] = __builtin_amdgcn_mfma_f32_16x16x32_bf16(a, B[t2][ks], acc[t2], 0, 0, 0);
    }

    // rows owned by this thread: rt*16 + quad*4 + r, r=0..3
    float4 dv = *(const float4*)(dis + rt * 16 + quad * 4);
    float dr[4] = {dv.x, dv.y, dv.z, dv.w};

#pragma unroll
    for (int t2 = 0; t2 < 4; ++t2) {
#pragma unroll
        for (int r = 0; r < 4; ++r) {
            int row = rt * 16 + quad * 4 + r;
            int c = w * 64 + t2 * 16 + m;
            out[(size_t)row * DIM + c] = f2bf(sane(acc[t2][r] * dr[r]));
        }
    }
}

// ---- aggregation + bias + ELU (round-1 structure, verbatim) -------------
// xw is pre-scaled by dis[src]; inner loop is pure gather+add.
// Wave = 1 node; 2 lane-halves process 2 edges per gather instruction with
// 16B loads (32 lanes x 16B = one 512B row per half). Per 8 edges:
// 1 broadcast int4 colidx load per half + 4 row gathers (5 VMEM instrs).
__global__ __launch_bounds__(256) void aggregate(const u16* __restrict__ xw,
                                                 const int* __restrict__ rowptr,
                                                 const int* __restrict__ colidx,
                                                 const float* __restrict__ dis,
                                                 const void* __restrict__ bias,
                                                 void* __restrict__ out,
                                                 const int* __restrict__ flags,
                                                 int final_layer) {
    int wid = threadIdx.x >> 6;
    int lane = threadIdx.x & 63;
    int node = blockIdx.x * 4 + wid;
    if (node >= N_NODES) return;
    int h = lane >> 5;          // half id: 0 -> even edge group, 1 -> odd
    int c8 = (lane & 31) * 8;   // 8-column base owned by this lane
    const u16* base = xw + c8;

    float2 a0 = make_float2(0.f, 0.f), a1 = a0, a2 = a0, a3 = a0;
    if (h == 0) {  // self term (xw already carries dis[node]) counted once
        uint4 v = *(const uint4*)(base + (size_t)node * DIM);
        a0 = cvt2(v.x); a1 = cvt2(v.y); a2 = cvt2(v.z); a3 = cvt2(v.w);
    }

#define ACC4(v)                                                   \
    do {                                                          \
        float2 t0 = cvt2((v).x), t1 = cvt2((v).y);                \
        float2 t2 = cvt2((v).z), t3 = cvt2((v).w);                \
        a0.x += t0.x; a0.y += t0.y; a1.x += t1.x; a1.y += t1.y;   \
        a2.x += t2.x; a2.y += t2.y; a3.x += t3.x; a3.y += t3.y;   \
    } while (0)

    int beg = rowptr[node];
    int end = rowptr[node + 1];
    int e = beg;

    // peel to 4-edge alignment so main-loop int4 colidx loads are 16B-aligned
    int pe = (beg + 3) & ~3;
    if (pe > end) pe = end;
    for (int t = e; t < pe; t += 2) {
        int idx = t + h;
        if (idx < pe) {
            int s = colidx[idx];
            uint4 v = *(const uint4*)(base + (size_t)s * DIM);
            ACC4(v);
        }
    }
    e = pe;

    int me = e + ((end - e) & ~7);
    int h4 = h * 4;
    for (; e < me; e += 8) {
        int4 c4 = *(const int4*)(colidx + e + h4);  // broadcast within half
        uint4 v0 = *(const uint4*)(base + (size_t)c4.x * DIM);
        uint4 v1 = *(const uint4*)(base + (size_t)c4.y * DIM);
        uint4 v2 = *(const uint4*)(base + (size_t)c4.z * DIM);
        uint4 v3 = *(const uint4*)(base + (size_t)c4.w * DIM);
        ACC4(v0); ACC4(v1); ACC4(v2); ACC4(v3);
    }

    for (; e < end; e += 2) {
        int idx = e + h;
        if (idx < end) {
            int s = colidx[idx];
            uint4 v = *(const uint4*)(base + (size_t)s * DIM);
            ACC4(v);
        }
    }
#undef ACC4

    // combine the two halves (each col summed across both edge groups)
    a0.x += __shfl_xor(a0.x, 32); a0.y += __shfl_xor(a0.y, 32);
    a1.x += __shfl_xor(a1.x, 32); a1.y += __shfl_xor(a1.y, 32);
    a2.x += __shfl_xor(a2.x, 32); a2.y += __shfl_xor(a2.y, 32);
    a3.x += __shfl_xor(a3.x, 32); a3.y += __shfl_xor(a3.y, 32);

    // low half stores cols c8+0..3 (a0,a1), high half c8+4..7 (a2,a3)
    float s0, s1, s2, s3;
    if (h == 0) { s0 = a0.x; s1 = a0.y; s2 = a1.x; s3 = a1.y; }
    else        { s0 = a2.x; s1 = a2.y; s2 = a3.x; s3 = a3.y; }
    int c0 = c8 + h * 4;

    float dn = dis[node];
    float b0, b1, b2, b3;
    int f32mode = flags[0];
    if (f32mode) {
        float4 bv = *(const float4*)((const float*)bias + c0);
        b0 = bv.x; b1 = bv.y; b2 = bv.z; b3 = bv.w;
    } else {
        ushort4 bv = *(const ushort4*)((const u16*)bias + c0);
        b0 = bf2f(bv.x); b1 = bf2f(bv.y); b2 = bf2f(bv.z); b3 = bf2f(bv.w);
    }
    float o0 = dn * s0 + b0;
    float o1 = dn * s1 + b1;
    float o2 = dn * s2 + b2;
    float o3 = dn * s3 + b3;
    o0 = sane(o0 > 0.f ? o0 : expm1f(o0));
    o1 = sane(o1 > 0.f ? o1 : expm1f(o1));
    o2 = sane(o2 > 0.f ? o2 : expm1f(o2));
    o3 = sane(o3 > 0.f ? o3 : expm1f(o3));
    if (final_layer && f32mode) {
        float4 ov; ov.x = o0; ov.y = o1; ov.z = o2; ov.w = o3;
        *(float4*)((float*)out + (size_t)node * DIM + c0) = ov;
    } else {
        ushort4 ov;
        ov.x = f2bf(o0); ov.y = f2bf(o1); ov.z = f2bf(o2); ov.w = f2bf(o3);
        *(ushort4*)((u16*)out + (size_t)node * DIM + c0) = ov;
    }
}

// ---- launch -------------------------------------------------------------
extern "C" void kernel_launch(void* const* d_in, const int* in_sizes, int n_in,
                              void* d_out, int out_size, void* d_ws, size_t ws_size,
                              hipStream_t stream) {
    const void* x  = d_in[0];
    const int*  ei = (const int*)d_in[1];
    const void* W1 = d_in[2];
    const void* b1 = d_in[3];
    const void* W2 = d_in[4];
    const void* b2 = d_in[5];

    char* ws = (char*)d_ws;
    size_t off = 0;
    auto alloc = [&](size_t bytes) {
        void* p = ws + off;
        off = (off + bytes + 255) & ~(size_t)255;
        return p;
    };
    int*   flags    = (int*)alloc(256);
    int*   rowcount = (int*)alloc((size_t)N_NODES * 4);
    int*   rowptr   = (int*)alloc((size_t)(N_NODES + 1) * 4);
    int*   cursor   = (int*)alloc((size_t)N_NODES * 4);
    int*   colidx   = (int*)alloc((size_t)N_EDGES * 4);
    float* dis      = (float*)alloc((size_t)N_NODES * 4);
    int*   bsum     = (int*)alloc((size_t)SCAN_NBLK * 4 + 256);
    u16*   Wt1      = (u16*)alloc((size_t)DIM * DIM * 2);
    u16*   Wt2      = (u16*)alloc((size_t)DIM * DIM * 2);
    u16*   xw       = (u16*)alloc((size_t)N_NODES * DIM * 2);
    (void)ws_size;

    // src32/dst32 alias the xw region: their lifetime (count_convert..fill
    // passes) ends before gemm_mfma first writes xw.
    int* src32 = (int*)xw;
    int* dst32 = src32 + N_EDGES;

    detect_kernel<<<1, 64, 0, stream>>>((const u32*)x, ei, flags);
    hipMemsetAsync(rowcount, 0, (size_t)N_NODES * 4, stream);
    count_convert<<<(N_EDGES + 255) / 256, 256, 0, stream>>>(ei, rowcount, src32, dst32, flags);
    scan_block_sums<<<SCAN_NBLK, SCAN_B, 0, stream>>>(rowcount, bsum);
    scan_bsum<<<1, 128, 0, stream>>>(bsum, rowptr);
    scan_final<<<SCAN_NBLK, SCAN_B, 0, stream>>>(rowcount, bsum, rowptr, cursor, dis);
    for (int p = 0; p < NPASS; ++p)
        fill_csr_pass<<<(N_EDGES + 255) / 256, 256, 0, stream>>>(src32, dst32, cursor,
                                                                 colidx, p * WIN);
    transpose_w2<<<DIM, DIM, 0, stream>>>(W1, W2, Wt1, Wt2, flags);

    // layer 1 (gemm reads x directly; converts/scrubs in the A-load path)
    gemm_mfma<<<N_NODES / 16, 256, 0, stream>>>(x, Wt1, dis, xw, flags, 1);
    aggregate<<<N_NODES / 4, 256, 0, stream>>>(xw, rowptr, colidx, dis, b1, d_out, flags, 0);

    // layer 2
    gemm_mfma<<<N_NODES / 16, 256, 0, stream>>>(d_out, Wt2, dis, xw, flags, 0);
    aggregate<<<N_NODES / 4, 256, 0, stream>>>(xw, rowptr, colidx, dis, b2, d_out, flags, 1);
}

// Round 5
// 1111.069 us; speedup vs baseline: 9.0368x; 1.0815x over previous
//
#include <hip/hip_runtime.h>
#include <math.h>

#define N_NODES 100000
#define N_EDGES 3200000
#define DIM 256
#define SCAN_B 1024
#define NPASS 8
#define WIN ((N_NODES + NPASS - 1) / NPASS)  // 12500

// src-window bucketing: within each dst row, edges grouped by src>>WSH.
// key = dst*NWIN + (src>>WSH); buckets of a row are contiguous -> row's
// colidx segment is sorted by 2MB src-window => phase-aligned L2 sweep.
#define WSH 12
#define NWIN 25                                   // ceil(100000/4096)
#define NBUCK (N_NODES * NWIN)                    // 2,500,000
#define SCAN_GRID_W ((NBUCK + SCAN_B - 1) / SCAN_B)   // 2442
#define BS_CHUNK ((SCAN_GRID_W + 1023) / 1024)        // 3

typedef unsigned short u16;
typedef unsigned int u32;
typedef __attribute__((ext_vector_type(8))) short bf16x8;
typedef __attribute__((ext_vector_type(4))) float f32x4;

__device__ __forceinline__ float bf2f(u16 u) {
    union { u32 i; float f; } v; v.i = ((u32)u) << 16; return v.f;
}
__device__ __forceinline__ u16 f2bf(float f) {
    union { float f; u32 i; } v; v.f = f;
    u32 x = v.i;
    return (u16)((x + 0x7fffu + ((x >> 16) & 1u)) >> 16);
}
__device__ __forceinline__ float sane(float v) {
    union { float f; u32 i; } u; u.f = v;
    if ((u.i & 0x7f800000u) == 0x7f800000u) return 0.f;
    return v;
}
__device__ __forceinline__ int iclamp(int v, int lo, int hi) {
    return v < lo ? lo : (v > hi ? hi : v);
}
// one dword holding 2 bf16 -> float2 (lo elem, hi elem)
__device__ __forceinline__ float2 cvt2(u32 d) {
    union { u32 i; float f; } lo, hi;
    lo.i = d << 16;
    hi.i = d & 0xffff0000u;
    return make_float2(lo.f, hi.f);
}

// ---- runtime format probes ----------------------------------------------
// flags[0]: 1 => float tensors are fp32, 0 => bf16
// flags[1]: 1 => edge_index is int64 (lo/hi word pairs), 0 => int32
__global__ void detect_kernel(const u32* __restrict__ xw_words,
                              const int* __restrict__ ei, int* __restrict__ flags) {
    int lane = threadIdx.x;
    int cnt = 0;
#pragma unroll
    for (int j = 0; j < 4; ++j) {
        u32 e = (xw_words[lane + 64 * j] >> 7) & 0xffu;
        cnt += (e >= 0x70 && e <= 0x88) ? 1 : 0;
    }
    int nz = 0;
#pragma unroll
    for (int j = 0; j < 4; ++j) nz += (ei[2 * (lane + 64 * j) + 1] != 0) ? 1 : 0;
#pragma unroll
    for (int off = 32; off; off >>= 1) {
        cnt += __shfl_down(cnt, off, 64);
        nz += __shfl_down(nz, off, 64);
    }
    if (lane == 0) {
        flags[0] = (cnt < 128) ? 1 : 0;
        flags[1] = (nz == 0) ? 1 : 0;
    }
}

__device__ __forceinline__ int edge_val(const int* __restrict__ ei, int which,
                                        int i, int f64) {
    long long idx = (long long)which * N_EDGES + i;
    int v = f64 ? ei[idx * 2] : ei[idx];
    return iclamp(v, 0, N_NODES - 1);
}

// ---- bucket-CSR build: count per (dst, src-window) ----------------------
__global__ void count_convert(const int* __restrict__ ei, int* __restrict__ cnt2,
                              int* __restrict__ src32, int* __restrict__ dst32,
                              const int* __restrict__ flags) {
    int i = blockIdx.x * blockDim.x + threadIdx.x;
    if (i < N_EDGES) {
        int f = flags[1];
        int s = edge_val(ei, 0, i, f);
        int d = edge_val(ei, 1, i, f);
        src32[i] = s;
        dst32[i] = d;
        atomicAdd(&cnt2[d * NWIN + (s >> WSH)], 1);
    }
}

// ---- parallel 3-phase exclusive scan over NBUCK elements ----------------
__global__ __launch_bounds__(SCAN_B) void scan_block_sums(const int* __restrict__ cnt,
                                                          int* __restrict__ bsum,
                                                          int M) {
    __shared__ int ws[16];
    int i = blockIdx.x * SCAN_B + threadIdx.x;
    int v = (i < M) ? cnt[i] : 0;
#pragma unroll
    for (int off = 32; off; off >>= 1) v += __shfl_down(v, off, 64);
    if ((threadIdx.x & 63) == 0) ws[threadIdx.x >> 6] = v;
    __syncthreads();
    if (threadIdx.x < 16) {
        int t = ws[threadIdx.x];
#pragma unroll
        for (int off = 8; off; off >>= 1) t += __shfl_down(t, off, 16);
        if (threadIdx.x == 0) bsum[blockIdx.x] = t;
    }
}

// single-block scan of SCAN_GRID_W block sums; 1024 thr x BS_CHUNK elems
__global__ __launch_bounds__(1024) void scan_bsum_big(int* __restrict__ bsum) {
    __shared__ int sd[1024];
    int t = threadIdx.x;
    int base = t * BS_CHUNK;
    int v[BS_CHUNK];
    int s = 0;
#pragma unroll
    for (int j = 0; j < BS_CHUNK; ++j) {
        v[j] = (base + j < SCAN_GRID_W) ? bsum[base + j] : 0;
        s += v[j];
    }
    sd[t] = s;
    __syncthreads();
    for (int off = 1; off < 1024; off <<= 1) {
        int x = (t >= off) ? sd[t - off] : 0;
        __syncthreads();
        sd[t] += x;
        __syncthreads();
    }
    int ex = sd[t] - s;
#pragma unroll
    for (int j = 0; j < BS_CHUNK; ++j) {
        if (base + j < SCAN_GRID_W) { bsum[base + j] = ex; ex += v[j]; }
    }
}

__global__ __launch_bounds__(SCAN_B) void scan_final_w(const int* __restrict__ cnt,
                                                       const int* __restrict__ bsum,
                                                       int* __restrict__ rowptr,
                                                       int* __restrict__ cursor,
                                                       int M) {
    __shared__ int ws[16];
    int lane = threadIdx.x & 63;
    int wid = threadIdx.x >> 6;
    int i = blockIdx.x * SCAN_B + threadIdx.x;
    int c = (i < M) ? cnt[i] : 0;
    int v = c;
#pragma unroll
    for (int off = 1; off < 64; off <<= 1) {
        int t = __shfl_up(v, off, 64);
        if (lane >= off) v += t;
    }
    if (lane == 63) ws[wid] = v;
    __syncthreads();
    int woff = 0;
    for (int w = 0; w < wid; ++w) woff += ws[w];
    int excl = bsum[blockIdx.x] + woff + v - c;
    if (i < M) { rowptr[i] = excl; cursor[i] = excl; }
    if (blockIdx.x == 0 && threadIdx.x == 0) rowptr[M] = N_EDGES;
}

// dis from bucket-boundary differences (after scan): indeg of node i is
// rowptr2[(i+1)*NWIN] - rowptr2[i*NWIN]
__global__ void dis_kernel(const int* __restrict__ rowptr2, float* __restrict__ dis) {
    int i = blockIdx.x * blockDim.x + threadIdx.x;
    if (i < N_NODES) {
        int indeg = rowptr2[(i + 1) * NWIN] - rowptr2[i * NWIN];
        indeg = iclamp(indeg, 0, N_EDGES);
        dis[i] = rsqrtf((float)(indeg + 1));  // +1 self loop
    }
}

// ---- windowed CSR fill: pass p handles dst in [lo, lo+WIN) --------------
// write window (row segments of 12500 dst) stays ~1.6MB L2-resident; within
// each row, bucket order gives src-window-sorted colidx for free.
__global__ void fill_csr_pass(const int* __restrict__ src32,
                              const int* __restrict__ dst32,
                              int* __restrict__ cursor2, int* __restrict__ colidx,
                              int lo) {
    int i = blockIdx.x * blockDim.x + threadIdx.x;
    if (i < N_EDGES) {
        int d = dst32[i];
        if ((unsigned)(d - lo) < (unsigned)WIN) {
            int s = src32[i];
            int pos = atomicAdd(&cursor2[d * NWIN + (s >> WSH)], 1);
            colidx[pos] = s;
        }
    }
}

// ---- both weight transposes in one launch (dtype-aware) -----------------
__global__ void transpose_w2(const void* __restrict__ W1, const void* __restrict__ W2,
                             u16* __restrict__ Wt1, u16* __restrict__ Wt2,
                             const int* __restrict__ flags) {
    int n = blockIdx.x;
    int k = threadIdx.x;
    int f32mode = flags[0];
    float v1 = f32mode ? ((const float*)W1)[k * DIM + n]
                       : bf2f(((const u16*)W1)[k * DIM + n]);
    float v2 = f32mode ? ((const float*)W2)[k * DIM + n]
                       : bf2f(((const u16*)W2)[k * DIM + n]);
    Wt1[n * DIM + k] = f2bf(sane(v1));
    Wt2[n * DIM + k] = f2bf(sane(v2));
}

// ---- dense GEMM: register-resident B, 64 rows/block ---------------------
// out[row] = bf16( dis[row] * (A[row] @ W) ).  B-frags stay in VGPRs across
// 4 row-subtiles -> Wt L2 refetch cut 4x (800 -> 200 MB/layer).
// A-load path converts/scrubs in place (first=1: A may be fp32).
__global__ __launch_bounds__(256) void gemm_mfma(const void* __restrict__ Ain,
                                                 const u16* __restrict__ Wt,
                                                 const float* __restrict__ dis,
                                                 u16* __restrict__ out,
                                                 const int* __restrict__ flags,
                                                 int first) {
    int w = threadIdx.x >> 6;   // col-group 0..3
    int lane = threadIdx.x & 63;
    int m = lane & 15;
    int quad = lane >> 4;

    bf16x8 B[4][8];
#pragma unroll
    for (int t2 = 0; t2 < 4; ++t2)
#pragma unroll
        for (int ks = 0; ks < 8; ++ks)
            B[t2][ks] = *(const bf16x8*)(Wt + (size_t)((w * 4 + t2) * 16 + m) * DIM +
                                         ks * 32 + quad * 8);

    int f32in = first ? flags[0] : 0;

    for (int rr = 0; rr < 4; ++rr) {
        int row0 = blockIdx.x * 64 + rr * 16;
        if (row0 >= N_NODES) break;
        size_t rowoff = (size_t)(row0 + m) * DIM + quad * 8;  // element offset
        f32x4 acc[4];
#pragma unroll
        for (int t2 = 0; t2 < 4; ++t2) acc[t2] = (f32x4){0.f, 0.f, 0.f, 0.f};

#pragma unroll
        for (int ks = 0; ks < 8; ++ks) {
            bf16x8 a;
            if (f32in) {
                const float* ap = (const float*)Ain + rowoff + ks * 32;
                float4 f0 = *(const float4*)ap;
                float4 f1 = *(const float4*)(ap + 4);
                a[0] = (short)f2bf(sane(f0.x)); a[1] = (short)f2bf(sane(f0.y));
                a[2] = (short)f2bf(sane(f0.z)); a[3] = (short)f2bf(sane(f0.w));
                a[4] = (short)f2bf(sane(f1.x)); a[5] = (short)f2bf(sane(f1.y));
                a[6] = (short)f2bf(sane(f1.z)); a[7] = (short)f2bf(sane(f1.w));
            } else {
                union { bf16x8 v; u32 d[4]; } U;
                U.v = *(const bf16x8*)((const u16*)Ain + rowoff + ks * 32);
#pragma unroll
                for (int j = 0; j < 4; ++j) {   // scrub inf/nan bf16 -> 0
                    u32 x = U.d[j];
                    if ((x & 0x7f800000u) == 0x7f800000u) x &= 0x0000ffffu;
                    if ((x & 0x00007f80u) == 0x00007f80u) x &= 0xffff0000u;
                    U.d[j] = x;
                }
                a = U.v;
            }
#pragma unroll
            for (int t2 = 0; t2 < 4; ++t2)
                acc[t2] = __builtin_amdgcn_mfma_f32_16x16x32_bf16(a, B[t2][ks], acc[t2], 0, 0, 0);
        }

        float4 dv = *(const float4*)(dis + row0 + quad * 4);
        float dr[4] = {dv.x, dv.y, dv.z, dv.w};

#pragma unroll
        for (int t2 = 0; t2 < 4; ++t2) {
#pragma unroll
            for (int r = 0; r < 4; ++r) {
                int row = row0 + quad * 4 + r;
                int c = w * 64 + t2 * 16 + m;
                out[(size_t)row * DIM + c] = f2bf(sane(acc[t2][r] * dr[r]));
            }
        }
    }
}

// ---- aggregation + bias + ELU (round-1 hot loop, verbatim) --------------
// xw is pre-scaled by dis[src]; colidx within each row is src-window-sorted
// so all waves sweep xw front-to-back in phase (L2-resident window).
__global__ __launch_bounds__(256) void aggregate(const u16* __restrict__ xw,
                                                 const int* __restrict__ rowptr2,
                                                 const int* __restrict__ colidx,
                                                 const float* __restrict__ dis,
                                                 const void* __restrict__ bias,
                                                 void* __restrict__ out,
                                                 const int* __restrict__ flags,
                                                 int final_layer) {
    int wid = threadIdx.x >> 6;
    int lane = threadIdx.x & 63;
    int node = blockIdx.x * 4 + wid;
    if (node >= N_NODES) return;
    int h = lane >> 5;          // half id: 0 -> even edge group, 1 -> odd
    int c8 = (lane & 31) * 8;   // 8-column base owned by this lane
    const u16* base = xw + c8;

    float2 a0 = make_float2(0.f, 0.f), a1 = a0, a2 = a0, a3 = a0;
    if (h == 0) {  // self term (xw already carries dis[node]) counted once
        uint4 v = *(const uint4*)(base + (size_t)node * DIM);
        a0 = cvt2(v.x); a1 = cvt2(v.y); a2 = cvt2(v.z); a3 = cvt2(v.w);
    }

#define ACC4(v)                                                   \
    do {                                                          \
        float2 t0 = cvt2((v).x), t1 = cvt2((v).y);                \
        float2 t2 = cvt2((v).z), t3 = cvt2((v).w);                \
        a0.x += t0.x; a0.y += t0.y; a1.x += t1.x; a1.y += t1.y;   \
        a2.x += t2.x; a2.y += t2.y; a3.x += t3.x; a3.y += t3.y;   \
    } while (0)

    int beg = rowptr2[node * NWIN];
    int end = rowptr2[node * NWIN + NWIN];
    int e = beg;

    // peel to 4-edge alignment so main-loop int4 colidx loads are 16B-aligned
    int pe = (beg + 3) & ~3;
    if (pe > end) pe = end;
    for (int t = e; t < pe; t += 2) {
        int idx = t + h;
        if (idx < pe) {
            int s = colidx[idx];
            uint4 v = *(const uint4*)(base + (size_t)s * DIM);
            ACC4(v);
        }
    }
    e = pe;

    int me = e + ((end - e) & ~7);
    int h4 = h * 4;
    for (; e < me; e += 8) {
        int4 c4 = *(const int4*)(colidx + e + h4);  // broadcast within half
        uint4 v0 = *(const uint4*)(base + (size_t)c4.x * DIM);
        uint4 v1 = *(const uint4*)(base + (size_t)c4.y * DIM);
        uint4 v2 = *(const uint4*)(base + (size_t)c4.z * DIM);
        uint4 v3 = *(const uint4*)(base + (size_t)c4.w * DIM);
        ACC4(v0); ACC4(v1); ACC4(v2); ACC4(v3);
    }

    for (; e < end; e += 2) {
        int idx = e + h;
        if (idx < end) {
            int s = colidx[idx];
            uint4 v = *(const uint4*)(base + (size_t)s * DIM);
            ACC4(v);
        }
    }
#undef ACC4

    // combine the two halves (each col summed across both edge groups)
    a0.x += __shfl_xor(a0.x, 32); a0.y += __shfl_xor(a0.y, 32);
    a1.x += __shfl_xor(a1.x, 32); a1.y += __shfl_xor(a1.y, 32);
    a2.x += __shfl_xor(a2.x, 32); a2.y += __shfl_xor(a2.y, 32);
    a3.x += __shfl_xor(a3.x, 32); a3.y += __shfl_xor(a3.y, 32);

    // low half stores cols c8+0..3 (a0,a1), high half c8+4..7 (a2,a3)
    float s0, s1, s2, s3;
    if (h == 0) { s0 = a0.x; s1 = a0.y; s2 = a1.x; s3 = a1.y; }
    else        { s0 = a2.x; s1 = a2.y; s2 = a3.x; s3 = a3.y; }
    int c0 = c8 + h * 4;

    float dn = dis[node];
    float b0, b1, b2, b3;
    int f32mode = flags[0];
    if (f32mode) {
        float4 bv = *(const float4*)((const float*)bias + c0);
        b0 = bv.x; b1 = bv.y; b2 = bv.z; b3 = bv.w;
    } else {
        ushort4 bv = *(const ushort4*)((const u16*)bias + c0);
        b0 = bf2f(bv.x); b1 = bf2f(bv.y); b2 = bf2f(bv.z); b3 = bf2f(bv.w);
    }
    float o0 = dn * s0 + b0;
    float o1 = dn * s1 + b1;
    float o2 = dn * s2 + b2;
    float o3 = dn * s3 + b3;
    o0 = sane(o0 > 0.f ? o0 : expm1f(o0));
    o1 = sane(o1 > 0.f ? o1 : expm1f(o1));
    o2 = sane(o2 > 0.f ? o2 : expm1f(o2));
    o3 = sane(o3 > 0.f ? o3 : expm1f(o3));
    if (final_layer && f32mode) {
        float4 ov; ov.x = o0; ov.y = o1; ov.z = o2; ov.w = o3;
        *(float4*)((float*)out + (size_t)node * DIM + c0) = ov;
    } else {
        ushort4 ov;
        ov.x = f2bf(o0); ov.y = f2bf(o1); ov.z = f2bf(o2); ov.w = f2bf(o3);
        *(ushort4*)((u16*)out + (size_t)node * DIM + c0) = ov;
    }
}

// ---- launch -------------------------------------------------------------
extern "C" void kernel_launch(void* const* d_in, const int* in_sizes, int n_in,
                              void* d_out, int out_size, void* d_ws, size_t ws_size,
                              hipStream_t stream) {
    const void* x  = d_in[0];
    const int*  ei = (const int*)d_in[1];
    const void* W1 = d_in[2];
    const void* b1 = d_in[3];
    const void* W2 = d_in[4];
    const void* b2 = d_in[5];

    char* ws = (char*)d_ws;
    size_t off = 0;
    auto alloc = [&](size_t bytes) {
        void* p = ws + off;
        off = (off + bytes + 255) & ~(size_t)255;
        return p;
    };
    int*   flags   = (int*)alloc(256);
    int*   rowptr2 = (int*)alloc(((size_t)NBUCK + 1) * 4);  // 10 MB, persists
    int*   colidx  = (int*)alloc((size_t)N_EDGES * 4);      // 12.8 MB
    float* dis     = (float*)alloc((size_t)N_NODES * 4);
    int*   bsum    = (int*)alloc((size_t)SCAN_GRID_W * 4 + 256);
    u16*   Wt1     = (u16*)alloc((size_t)DIM * DIM * 2);
    u16*   Wt2     = (u16*)alloc((size_t)DIM * DIM * 2);
    u16*   xw      = (u16*)alloc((size_t)N_NODES * DIM * 2); // 51.2 MB
    (void)ws_size;

    // CSR-build temporaries alias the xw region (dead before gemm writes xw):
    // src32 12.8MB | dst32 12.8MB | cnt2 10MB (cursor2 aliases cnt2: each
    // scan_final_w thread reads cnt[i] before writing cursor[i] in-place)
    char* xwb = (char*)xw;
    int* src32  = (int*)xwb;
    int* dst32  = (int*)(xwb + (size_t)N_EDGES * 4);
    int* cnt2   = (int*)(xwb + (size_t)N_EDGES * 8);
    int* cursor2 = cnt2;

    detect_kernel<<<1, 64, 0, stream>>>((const u32*)x, ei, flags);
    hipMemsetAsync(cnt2, 0, (size_t)NBUCK * 4, stream);
    count_convert<<<(N_EDGES + 255) / 256, 256, 0, stream>>>(ei, cnt2, src32, dst32, flags);
    scan_block_sums<<<SCAN_GRID_W, SCAN_B, 0, stream>>>(cnt2, bsum, NBUCK);
    scan_bsum_big<<<1, 1024, 0, stream>>>(bsum);
    scan_final_w<<<SCAN_GRID_W, SCAN_B, 0, stream>>>(cnt2, bsum, rowptr2, cursor2, NBUCK);
    dis_kernel<<<(N_NODES + 255) / 256, 256, 0, stream>>>(rowptr2, dis);
    for (int p = 0; p < NPASS; ++p)
        fill_csr_pass<<<(N_EDGES + 255) / 256, 256, 0, stream>>>(src32, dst32, cursor2,
                                                                 colidx, p * WIN);
    transpose_w2<<<DIM, DIM, 0, stream>>>(W1, W2, Wt1, Wt2, flags);

    // layer 1 (gemm reads x directly; converts/scrubs in the A-load path)
    gemm_mfma<<<(N_NODES + 63) / 64, 256, 0, stream>>>(x, Wt1, dis, xw, flags, 1);
    aggregate<<<N_NODES / 4, 256, 0, stream>>>(xw, rowptr2, colidx, dis, b1, d_out, flags, 0);

    // layer 2
    gemm_mfma<<<(N_NODES + 63) / 64, 256, 0, stream>>>(d_out, Wt2, dis, xw, flags, 0);
    aggregate<<<N_NODES / 4, 256, 0, stream>>>(xw, rowptr2, colidx, dis, b2, d_out, flags, 1);
}